// Round 2
// baseline (108.362 us; speedup 1.0000x reference)
//
#include <hip/hip_runtime.h>
#include <stdint.h>

// Problem constants (fixed by reference file)
#define N_NODES 50000
#define KDEG    16
#define NFEAT   128
#define NTPL    16
#define MTPL    8
#define NTILES  ((N_NODES + 63) / 64)     // zbuild: 64 rows per block

// Workspace layout (floats):
//   [0    .. 2047]  tmean[t*128 + f]        (fallback path only)
//   [2048 .. 2063]  tsq[t]
//   [2064 .. 2079]  mCt[t]
//   [2080 .. 2095]  mCt2[t]
//   [2112 .. ]      node records, 32 floats (128B) each:
//                   rec[n] = { z[n][0..15] (f32), dst[n][0..15] (i32) }
#define TMEAN_OFF 0
#define TSQ_OFF   2048
#define MCT_OFF   2064
#define MCT2_OFF  2080
#define Z_OFF     2112                    // 2112 floats = 8448 B, 128B-aligned
#define ZROW      32                      // floats per node record
#define WS_FLOATS (Z_OFF + N_NODES * ZROW)
#define WS_BYTES  ((size_t)WS_FLOATS * 4)

// ---- DPP reduction helpers (VALU pipe, no LDS) ------------------------------
template<int CTRL>
__device__ __forceinline__ float dpp_addf(float v) {
    int t = __builtin_amdgcn_update_dpp(0, __float_as_int(v), CTRL, 0xF, 0xF, 1);
    return v + __int_as_float(t);
}
template<int CTRL>
__device__ __forceinline__ int dpp_addi(int v) {
    int t = __builtin_amdgcn_update_dpp(0, v, CTRL, 0xF, 0xF, 1);
    return v + t;
}
#define ROR1 0x121
#define ROR2 0x122
#define ROR4 0x124
#define ROR8 0x128
#define QPX1 0xB1
#define QPX2 0x4E

__device__ __forceinline__ float row16_sum(float v) {   // sum over 16-lane row
    v = dpp_addf<ROR1>(v);
    v = dpp_addf<ROR2>(v);
    v = dpp_addf<ROR4>(v);
    v = dpp_addf<ROR8>(v);
    return v;
}
__device__ __forceinline__ float row8_sum(float v) {    // sum of 8 consecutive
    v = dpp_addf<ROR1>(v);                              // lanes (mod-16 row)
    v = dpp_addf<ROR2>(v);
    v = dpp_addf<ROR4>(v);
    return v;
}
__device__ __forceinline__ int row16_sumi(int v) {
    v = dpp_addi<ROR1>(v);
    v = dpp_addi<ROR2>(v);
    v = dpp_addi<ROR4>(v);
    v = dpp_addi<ROR8>(v);
    return v;
}
__device__ __forceinline__ float quad_sum(float v) {    // sum over 4-lane quad
    v = dpp_addf<QPX1>(v);
    v = dpp_addf<QPX2>(v);
    return v;
}

// ============ Kernel A: template stats + node records ========================
// R2 change: 128 threads/block, each lane computes TWO rows (rr, rr+32) per
// tmean fragment read -> LDS traffic per node halves (ds_read_b128 feeds 8
// FMAs instead of 4). VGPR ~120, __launch_bounds__(128,2) -> no spill.
__global__ __launch_bounds__(128, 2)
void ltfwg_zbuild(const float* __restrict__ x,      // [N,128]
                  const int*   __restrict__ dst,    // [N,16]
                  const float* __restrict__ tmpl,   // [16,8,8]
                  const float* __restrict__ tfeat,  // [16,8,128]
                  float* __restrict__ ws) {
    const int tid = threadIdx.x;

    // tmean in LDS, skewed [t][q][36]: bank(t*144+q*36+4j) = (16t+4q+4j)%32
    __shared__ float tm_lds[NTPL * 144];

    {   // 128 threads: thread f does all 16 templates
        const int f = tid;
        #pragma unroll
        for (int t = 0; t < NTPL; ++t) {
            float s = 0.f;
            #pragma unroll
            for (int m = 0; m < MTPL; ++m)
                s += tfeat[t * (MTPL * NFEAT) + m * NFEAT + f];
            tm_lds[t * 144 + (f >> 5) * 36 + (f & 31)] = s * 0.125f;
        }
    }

    // Block 0 additionally computes the 48 scalar stats kernel B needs.
    // 8 threads per template (t = tid>>3, j = tid&7), row8 DPP reduction.
    if (blockIdx.x == 0) {
        const int t = tid >> 3;
        const int j = tid & 7;
        float ssq = 0.f;
        #pragma unroll
        for (int m = 0; m < MTPL; ++m)
            #pragma unroll
            for (int c = 0; c < 16; ++c) {
                float v = tfeat[t * (MTPL * NFEAT) + m * NFEAT + j * 16 + c];
                ssq += v * v;
            }
        float sv = 0.f, sv2 = 0.f;
        #pragma unroll
        for (int c = 0; c < 8; ++c) {
            float v = tmpl[t * 64 + j * 8 + c];
            sv += v;
            sv2 += v * v;
        }
        ssq = row8_sum(ssq);
        sv  = row8_sum(sv);
        sv2 = row8_sum(sv2);
        if (j == 0) {
            ws[TSQ_OFF + t]  = ssq * 0.125f;
            ws[MCT_OFF + t]  = sv  * (1.f / 64.f);
            ws[MCT2_OFF + t] = sv2 * (1.f / 64.f);
        }
    }
    __syncthreads();

    // z phase: 4 lanes per row (q = feature quarter), 2 rows per lane
    const int q  = tid & 3;
    const int rr = tid >> 2;              // 0..31
    const int4* d4 = (const int4*)dst;
    for (int tile = blockIdx.x; tile < NTILES; tile += gridDim.x) {
        const int n0 = tile * 64 + rr;
        const int n1 = n0 + 32;
        const bool p0 = (n0 < N_NODES);
        const bool p1 = (n1 < N_NODES);

        float4 xv0[8], xv1[8];
        int4 dv0 = make_int4(0, 0, 0, 0), dv1 = make_int4(0, 0, 0, 0);
        if (p0) {
            const float4* x4 = (const float4*)x + (size_t)n0 * 32 + q * 8;
            #pragma unroll
            for (int jj = 0; jj < 8; ++jj) xv0[jj] = x4[jj];
            dv0 = d4[(size_t)n0 * 4 + q];
        } else {
            #pragma unroll
            for (int jj = 0; jj < 8; ++jj) xv0[jj] = make_float4(0.f, 0.f, 0.f, 0.f);
        }
        if (p1) {
            const float4* x4 = (const float4*)x + (size_t)n1 * 32 + q * 8;
            #pragma unroll
            for (int jj = 0; jj < 8; ++jj) xv1[jj] = x4[jj];
            dv1 = d4[(size_t)n1 * 4 + q];
        } else {
            #pragma unroll
            for (int jj = 0; jj < 8; ++jj) xv1[jj] = make_float4(0.f, 0.f, 0.f, 0.f);
        }

        float s20 = 0.f, s21 = 0.f;
        #pragma unroll
        for (int jj = 0; jj < 8; ++jj) {
            s20 += xv0[jj].x * xv0[jj].x + xv0[jj].y * xv0[jj].y +
                   xv0[jj].z * xv0[jj].z + xv0[jj].w * xv0[jj].w;
            s21 += xv1[jj].x * xv1[jj].x + xv1[jj].y * xv1[jj].y +
                   xv1[jj].z * xv1[jj].z + xv1[jj].w * xv1[jj].w;
        }

        float acc0[NTPL], acc1[NTPL];
        #pragma unroll
        for (int t = 0; t < NTPL; ++t) {
            const float* tb = tm_lds + t * 144 + q * 36;
            float a0 = 0.f, a1 = 0.f;
            #pragma unroll
            for (int jj = 0; jj < 8; ++jj) {
                float4 tv = *(const float4*)(tb + 4 * jj);   // 1 ds_read_b128
                a0 += xv0[jj].x * tv.x + xv0[jj].y * tv.y +  // feeds 8 FMAs
                      xv0[jj].z * tv.z + xv0[jj].w * tv.w;
                a1 += xv1[jj].x * tv.x + xv1[jj].y * tv.y +
                      xv1[jj].z * tv.z + xv1[jj].w * tv.w;
            }
            acc0[t] = a0;
            acc1[t] = a1;
        }

        float h0 = quad_sum(s20) * 0.5f;
        float h1 = quad_sum(s21) * 0.5f;
        #pragma unroll
        for (int t = 0; t < NTPL; ++t) {
            acc0[t] = quad_sum(acc0[t]);
            acc1[t] = quad_sum(acc1[t]);
        }

        float b00, b01, b02, b03, b10, b11, b12, b13;
        if (q == 0)      { b00=acc0[0];  b01=acc0[1];  b02=acc0[2];  b03=acc0[3];
                           b10=acc1[0];  b11=acc1[1];  b12=acc1[2];  b13=acc1[3];  }
        else if (q == 1) { b00=acc0[4];  b01=acc0[5];  b02=acc0[6];  b03=acc0[7];
                           b10=acc1[4];  b11=acc1[5];  b12=acc1[6];  b13=acc1[7];  }
        else if (q == 2) { b00=acc0[8];  b01=acc0[9];  b02=acc0[10]; b03=acc0[11];
                           b10=acc1[8];  b11=acc1[9];  b12=acc1[10]; b13=acc1[11]; }
        else             { b00=acc0[12]; b01=acc0[13]; b02=acc0[14]; b03=acc0[15];
                           b10=acc1[12]; b11=acc1[13]; b12=acc1[14]; b13=acc1[15]; }

        if (p0) {
            float4* rw = (float4*)(ws + Z_OFF) + (size_t)n0 * 8;
            rw[q] = make_float4(h0 - b00, h0 - b01, h0 - b02, h0 - b03);
            ((int4*)rw)[4 + q] = dv0;
        }
        if (p1) {
            float4* rw = (float4*)(ws + Z_OFF) + (size_t)n1 * 8;
            rw[q] = make_float4(h1 - b10, h1 - b11, h1 - b12, h1 - b13);
            ((int4*)rw)[4 + q] = dv1;
        }
    }
}

// ============ Kernel B: per-node gather + structure ==========================
// Lane mapping: a = lane&15 (neighbor slot), c = lane>>4 (16B chunk).
// Per neighbor: z chunk (rec[0..3]) and dst chunk (rec[4..7]) are in the SAME
// 128B line -> one line fetch per neighbor, second load is an L1 hit.
// One-node-deep software pipeline hides the random-load latency.
__global__ __launch_bounds__(256, 8)
void ltfwg_gather(const int* __restrict__ dst, const float* __restrict__ ws,
                  float* __restrict__ out) {
    const int lane   = threadIdx.x & 63;
    const int gwave  = (blockIdx.x * blockDim.x + threadIdx.x) >> 6;
    const int nwaves = (gridDim.x * blockDim.x) >> 6;
    const int a = lane & 15;
    const int c = lane >> 4;

    const int tl = c * 4 + (lane & 3);
    const float A  = 0.5f * (ws[TSQ_OFF + tl] + ws[MCT2_OFF + tl]);
    const float Bc = 0.5f - ws[MCT_OFF + tl];
    const bool writer = (lane & 15) < 4;
    const float4* rz = (const float4*)(ws + Z_OFF);   // record = 8 float4s
    const int4*   rd = (const int4*)(ws + Z_OFF);

    int n0 = gwave;
    int nbr0 = (n0 < N_NODES) ? dst[n0 * KDEG + a] : 0;
    float4 v0  = make_float4(0.f, 0.f, 0.f, 0.f);
    int4   cv0 = make_int4(0, 0, 0, 0);
    if (n0 < N_NODES) {
        v0  = rz[(size_t)nbr0 * 8 + c];
        cv0 = rd[(size_t)nbr0 * 8 + 4 + c];
    }
    int n1 = n0 + nwaves;
    int nbr1 = (n1 < N_NODES) ? dst[n1 * KDEG + a] : 0;

    while (n0 < N_NODES) {
        // issue next node's gathers (wave-uniform guard, no divergence)
        float4 v1  = make_float4(0.f, 0.f, 0.f, 0.f);
        int4   cv1 = make_int4(0, 0, 0, 0);
        if (n1 < N_NODES) {
            v1  = rz[(size_t)nbr1 * 8 + c];
            cv1 = rd[(size_t)nbr1 * 8 + 4 + c];
        }
        const int n2 = n1 + nwaves;
        int nbr2 = (n2 < N_NODES) ? dst[n2 * KDEG + a] : 0;

        // membership mask: bit b = any(cv0 == nbr_b), partial over this chunk
        uint32_t m = 0;
        #pragma unroll
        for (int b = 0; b < KDEG; ++b) {
            int vb = __builtin_amdgcn_readlane(nbr0, b);
            uint32_t hit = (uint32_t)((cv0.x == vb) | (cv0.y == vb) |
                                      (cv0.z == vb) | (cv0.w == vb));
            m |= hit << b;
        }
        // merge the 4 chunks of row a (lanes differing in bits 4,5) — DS
        m |= (uint32_t)__shfl_xor((int)m, 16);
        m |= (uint32_t)__shfl_xor((int)m, 32);
        int cm = row16_sumi(__popc(m));        // sum rowcounts over the 16 a's

        // z reduction over a within each 16-lane row — DPP
        float s0 = row16_sum(v0.x);
        float s1 = row16_sum(v0.y);
        float s2 = row16_sum(v0.z);
        float s3 = row16_sum(v0.w);

        if (writer) {
            int j = lane & 3;
            float dsel = (j == 0) ? s0 : (j == 1) ? s1 : (j == 2) ? s2 : s3;
            out[n0 * NTPL + tl] = 0.0625f * dsel + A + (float)cm * (1.f / 256.f) * Bc;
        }

        n0 = n1; nbr0 = nbr1; v0 = v1; cv0 = cv1;
        n1 = n2; nbr1 = nbr2;
    }
}

// ---------------- fallback path (proven R2 kernels, ws too small) ------------
__global__ void ltfwg_prep(const float* __restrict__ tmpl,
                           const float* __restrict__ tfeat,
                           float* __restrict__ ws) {
    const int t   = blockIdx.x;
    const int tid = threadIdx.x;
    float s = 0.f, ssq = 0.f;
    #pragma unroll
    for (int m = 0; m < MTPL; ++m) {
        float v = tfeat[t * (MTPL * NFEAT) + m * NFEAT + tid];
        s += v;
        ssq += v * v;
    }
    ws[TMEAN_OFF + t * NFEAT + tid] = s * 0.125f;
    __shared__ float red[128];
    red[tid] = ssq;
    __syncthreads();
    for (int o = 64; o > 0; o >>= 1) {
        if (tid < o) red[tid] += red[tid + o];
        __syncthreads();
    }
    if (tid == 0) ws[TSQ_OFF + t] = red[0] * 0.125f;
    if (tid < 64) {
        float v = tmpl[t * 64 + tid];
        float sv = v, sv2 = v * v;
        #pragma unroll
        for (int off = 32; off >= 1; off >>= 1) {
            sv  += __shfl_xor(sv, off);
            sv2 += __shfl_xor(sv2, off);
        }
        if (tid == 0) {
            ws[MCT_OFF + t]  = sv  * (1.f / 64.f);
            ws[MCT2_OFF + t] = sv2 * (1.f / 64.f);
        }
    }
}

__global__ __launch_bounds__(256, 4)
void ltfwg_fallback(const float* __restrict__ x, const int* __restrict__ dst,
                    const float* __restrict__ ws, float* __restrict__ out) {
    const int lane   = threadIdx.x & 63;
    const int wave   = (blockIdx.x * blockDim.x + threadIdx.x) >> 6;
    const int nwaves = (gridDim.x * blockDim.x) >> 6;
    float tm0[NTPL], tm1[NTPL];
    #pragma unroll
    for (int t = 0; t < NTPL; ++t) {
        float2 tv = ((const float2*)(ws + TMEAN_OFF + t * NFEAT))[lane];
        tm0[t] = tv.x;
        tm1[t] = tv.y;
    }
    const int tl = lane & 15;
    const float A  = 0.5f * (ws[TSQ_OFF + tl] + ws[MCT2_OFF + tl]);
    const float Bc = 0.5f - ws[MCT_OFF + tl];
    for (int n = wave; n < N_NODES; n += nwaves) {
        const int nbr = dst[n * KDEG + (lane & 15)];
        float fs0 = 0.f, fs1 = 0.f, sqa = 0.f;
        #pragma unroll
        for (int aa = 0; aa < KDEG; ++aa) {
            int nid = __shfl(nbr, aa);
            float2 fv = ((const float2*)x)[nid * (NFEAT / 2) + lane];
            fs0 += fv.x; fs1 += fv.y;
            sqa += fv.x * fv.x + fv.y * fv.y;
        }
        float dotp[NTPL];
        #pragma unroll
        for (int t = 0; t < NTPL; ++t) dotp[t] = fs0 * tm0[t] + fs1 * tm1[t];
        int nida = __shfl(nbr, lane >> 2);
        int4 cv = ((const int4*)(dst + nida * KDEG))[lane & 3];
        uint32_t m = 0;
        #pragma unroll
        for (int b = 0; b < KDEG; ++b) {
            int vb = __shfl(nbr, b);
            uint32_t hit = (uint32_t)((cv.x == vb) | (cv.y == vb) |
                                      (cv.z == vb) | (cv.w == vb));
            m |= hit << b;
        }
        m |= (uint32_t)__shfl_xor((int)m, 1);
        m |= (uint32_t)__shfl_xor((int)m, 2);
        float cnt = (float)__popc(m);
        #pragma unroll
        for (int off = 32; off >= 1; off >>= 1) {
            sqa += __shfl_xor(sqa, off);
            cnt += __shfl_xor(cnt, off);
            #pragma unroll
            for (int t = 0; t < NTPL; ++t) dotp[t] += __shfl_xor(dotp[t], off);
        }
        float dsel = dotp[0];
        #pragma unroll
        for (int t = 1; t < NTPL; ++t) dsel = (lane == t) ? dotp[t] : dsel;
        if (lane < NTPL) {
            float mC = cnt * (1.0f / 1024.0f);
            out[n * NTPL + lane] = 0.03125f * sqa - 0.0625f * dsel + A + mC * Bc;
        }
    }
}

extern "C" void kernel_launch(void* const* d_in, const int* in_sizes, int n_in,
                              void* d_out, int out_size, void* d_ws, size_t ws_size,
                              hipStream_t stream) {
    const float* x     = (const float*)d_in[0];
    const int*   edge  = (const int*)d_in[1];
    const float* tmpl  = (const float*)d_in[2];
    const float* tfeat = (const float*)d_in[3];
    float* ws  = (float*)d_ws;
    float* out = (float*)d_out;
    const int* dst = edge + (N_NODES * KDEG);

    if (ws_size >= WS_BYTES) {
        ltfwg_zbuild<<<NTILES, 128, 0, stream>>>(x, dst, tmpl, tfeat, ws);
        ltfwg_gather<<<2048, 256, 0, stream>>>(dst, ws, out);
    } else {
        ltfwg_prep<<<NTPL, 128, 0, stream>>>(tmpl, tfeat, ws);
        ltfwg_fallback<<<1024, 256, 0, stream>>>(x, dst, ws, out);
    }
}

// Round 3
// 102.901 us; speedup vs baseline: 1.0531x; 1.0531x over previous
//
#include <hip/hip_runtime.h>
#include <stdint.h>

// Problem constants (fixed by reference file)
#define N_NODES 50000
#define KDEG    16
#define NFEAT   128
#define NTPL    16
#define MTPL    8
#define NTILES  ((N_NODES + 63) / 64)     // zbuild: 64 rows per block

// Workspace layout (floats):
//   [0    .. 2047]  tmean[t*128 + f]        (fallback path only)
//   [2048 .. 2063]  tsq[t]
//   [2064 .. 2079]  mCt[t]
//   [2080 .. 2095]  mCt2[t]
//   [2112 .. ]      node records, 32 floats (128B) each:
//                   rec[n] = { z[n][0..15] (f32), dst[n][0..15] (i32) }
//                   -> the per-neighbor z-gather and adjacency-row gather hit
//                      the SAME 128B cache line (second load is an L1 hit).
#define TMEAN_OFF 0
#define TSQ_OFF   2048
#define MCT_OFF   2064
#define MCT2_OFF  2080
#define Z_OFF     2112                    // 2112 floats = 8448 B, 128B-aligned
#define ZROW      32                      // floats per node record
#define WS_FLOATS (Z_OFF + N_NODES * ZROW)
#define WS_BYTES  ((size_t)WS_FLOATS * 4)

// ---- DPP reduction helpers (VALU pipe, no LDS) ------------------------------
template<int CTRL>
__device__ __forceinline__ float dpp_addf(float v) {
    int t = __builtin_amdgcn_update_dpp(0, __float_as_int(v), CTRL, 0xF, 0xF, 1);
    return v + __int_as_float(t);
}
template<int CTRL>
__device__ __forceinline__ int dpp_addi(int v) {
    int t = __builtin_amdgcn_update_dpp(0, v, CTRL, 0xF, 0xF, 1);
    return v + t;
}
#define ROR1 0x121
#define ROR2 0x122
#define ROR4 0x124
#define ROR8 0x128
#define QPX1 0xB1
#define QPX2 0x4E

__device__ __forceinline__ float row16_sum(float v) {   // sum over 16-lane row
    v = dpp_addf<ROR1>(v);
    v = dpp_addf<ROR2>(v);
    v = dpp_addf<ROR4>(v);
    v = dpp_addf<ROR8>(v);
    return v;
}
__device__ __forceinline__ int row16_sumi(int v) {
    v = dpp_addi<ROR1>(v);
    v = dpp_addi<ROR2>(v);
    v = dpp_addi<ROR4>(v);
    v = dpp_addi<ROR8>(v);
    return v;
}
__device__ __forceinline__ float quad_sum(float v) {    // sum over 4-lane quad
    v = dpp_addf<QPX1>(v);
    v = dpp_addf<QPX2>(v);
    return v;
}

// ============ Kernel A: template stats (per-block, redundant) + node records =
// R6-proven shape: 1 row per 4 lanes, xv[8]+acc[16] ~ 84 VGPR, NO SPILLS.
// Also copies the node's dst row into the record (sequential r+w, ~1us).
__global__ __launch_bounds__(256, 4)
void ltfwg_zbuild(const float* __restrict__ x,      // [N,128]
                  const int*   __restrict__ dst,    // [N,16]
                  const float* __restrict__ tmpl,   // [16,8,8]
                  const float* __restrict__ tfeat,  // [16,8,128]
                  float* __restrict__ ws) {
    const int tid = threadIdx.x;

    // tmean in LDS, skewed [t][q][36]: bank(t*144+q*36+4j) = (16t+4q+4j)%32
    __shared__ float tm_lds[NTPL * 144];

    {   // all 256 threads: thread (f = tid&127, half = tid>>7) does 8 templates
        const int f  = tid & 127;
        const int t0 = (tid >> 7) * 8;
        #pragma unroll
        for (int k = 0; k < 8; ++k) {
            int t = t0 + k;
            float s = 0.f;
            #pragma unroll
            for (int m = 0; m < MTPL; ++m)
                s += tfeat[t * (MTPL * NFEAT) + m * NFEAT + f];
            tm_lds[t * 144 + (f >> 5) * 36 + (f & 31)] = s * 0.125f;
        }
    }

    // Block 0 additionally computes the 48 scalar stats kernel B needs.
    if (blockIdx.x == 0) {
        const int t = tid >> 4;      // 16 threads per template
        const int j = tid & 15;
        float ssq = 0.f;
        #pragma unroll
        for (int m = 0; m < MTPL; ++m)
            #pragma unroll
            for (int c = 0; c < 8; ++c) {
                float v = tfeat[t * (MTPL * NFEAT) + m * NFEAT + j * 8 + c];
                ssq += v * v;
            }
        float sv = 0.f, sv2 = 0.f;
        #pragma unroll
        for (int c = 0; c < 4; ++c) {
            float v = tmpl[t * 64 + j * 4 + c];
            sv += v;
            sv2 += v * v;
        }
        ssq = row16_sum(ssq);
        sv  = row16_sum(sv);
        sv2 = row16_sum(sv2);
        if (j == 0) {
            ws[TSQ_OFF + t]  = ssq * 0.125f;
            ws[MCT_OFF + t]  = sv  * (1.f / 64.f);
            ws[MCT2_OFF + t] = sv2 * (1.f / 64.f);
        }
    }
    __syncthreads();

    // z phase: 4 lanes per row (q = feature quarter), 64 rows per tile
    const int q  = tid & 3;
    const int rr = tid >> 2;
    const int4* d4 = (const int4*)dst;
    for (int tile = blockIdx.x; tile < NTILES; tile += gridDim.x) {
        int n = tile * 64 + rr;
        if (n < N_NODES) {
            const float4* x4 = (const float4*)x + (size_t)n * 32 + q * 8;
            float4 xv[8];
            #pragma unroll
            for (int jj = 0; jj < 8; ++jj) xv[jj] = x4[jj];
            // sequential dst-row chunk for the record copy (overlaps compute)
            int4 dv = d4[(size_t)n * 4 + q];

            float s2 = 0.f;
            #pragma unroll
            for (int jj = 0; jj < 8; ++jj)
                s2 += xv[jj].x * xv[jj].x + xv[jj].y * xv[jj].y +
                      xv[jj].z * xv[jj].z + xv[jj].w * xv[jj].w;

            float acc[NTPL];
            #pragma unroll
            for (int t = 0; t < NTPL; ++t) {
                const float* tb = tm_lds + t * 144 + q * 36;
                float a = 0.f;
                #pragma unroll
                for (int jj = 0; jj < 8; ++jj) {
                    float4 tv = *(const float4*)(tb + 4 * jj);
                    a += xv[jj].x * tv.x + xv[jj].y * tv.y +
                         xv[jj].z * tv.z + xv[jj].w * tv.w;
                }
                acc[t] = a;
            }

            float h = quad_sum(s2) * 0.5f;
            #pragma unroll
            for (int t = 0; t < NTPL; ++t) acc[t] = quad_sum(acc[t]);

            float b0, b1, b2, b3;
            if (q == 0)      { b0 = acc[0];  b1 = acc[1];  b2 = acc[2];  b3 = acc[3];  }
            else if (q == 1) { b0 = acc[4];  b1 = acc[5];  b2 = acc[6];  b3 = acc[7];  }
            else if (q == 2) { b0 = acc[8];  b1 = acc[9];  b2 = acc[10]; b3 = acc[11]; }
            else             { b0 = acc[12]; b1 = acc[13]; b2 = acc[14]; b3 = acc[15]; }
            float4* rw = (float4*)(ws + Z_OFF) + (size_t)n * 8;
            rw[q] = make_float4(h - b0, h - b1, h - b2, h - b3);
            ((int4*)rw)[4 + q] = dv;
        }
    }
}

// ============ Kernel B: per-node gather + structure ==========================
// Lane mapping: a = lane&15 (neighbor slot), c = lane>>4 (16B chunk).
// Per neighbor: z chunk (rec[0..3]) and dst chunk (rec[4..7]) are in the SAME
// 128B line -> one line fetch per neighbor, second load is an L1 hit.
// One-node-deep software pipeline: gathers for n1 issue before the compute of
// n0, hiding random-load latency under the membership/reduction VALU phase.
__global__ __launch_bounds__(256, 8)
void ltfwg_gather(const int* __restrict__ dst, const float* __restrict__ ws,
                  float* __restrict__ out) {
    const int lane   = threadIdx.x & 63;
    const int gwave  = (blockIdx.x * blockDim.x + threadIdx.x) >> 6;
    const int nwaves = (gridDim.x * blockDim.x) >> 6;
    const int a = lane & 15;
    const int c = lane >> 4;

    const int tl = c * 4 + (lane & 3);
    const float A  = 0.5f * (ws[TSQ_OFF + tl] + ws[MCT2_OFF + tl]);
    const float Bc = 0.5f - ws[MCT_OFF + tl];
    const bool writer = (lane & 15) < 4;
    const float4* rz = (const float4*)(ws + Z_OFF);   // record = 8 float4s
    const int4*   rd = (const int4*)(ws + Z_OFF);

    int n0 = gwave;
    int nbr0 = (n0 < N_NODES) ? dst[n0 * KDEG + a] : 0;
    float4 v0  = make_float4(0.f, 0.f, 0.f, 0.f);
    int4   cv0 = make_int4(0, 0, 0, 0);
    if (n0 < N_NODES) {
        v0  = rz[(size_t)nbr0 * 8 + c];
        cv0 = rd[(size_t)nbr0 * 8 + 4 + c];
    }
    int n1 = n0 + nwaves;
    int nbr1 = (n1 < N_NODES) ? dst[n1 * KDEG + a] : 0;

    while (n0 < N_NODES) {
        // issue next node's gathers (wave-uniform guard, no divergence)
        float4 v1  = make_float4(0.f, 0.f, 0.f, 0.f);
        int4   cv1 = make_int4(0, 0, 0, 0);
        if (n1 < N_NODES) {
            v1  = rz[(size_t)nbr1 * 8 + c];
            cv1 = rd[(size_t)nbr1 * 8 + 4 + c];
        }
        const int n2 = n1 + nwaves;
        int nbr2 = (n2 < N_NODES) ? dst[n2 * KDEG + a] : 0;

        // membership mask: bit b = any(cv0 == nbr_b), partial over this chunk
        uint32_t m = 0;
        #pragma unroll
        for (int b = 0; b < KDEG; ++b) {
            int vb = __builtin_amdgcn_readlane(nbr0, b);
            uint32_t hit = (uint32_t)((cv0.x == vb) | (cv0.y == vb) |
                                      (cv0.z == vb) | (cv0.w == vb));
            m |= hit << b;
        }
        // merge the 4 chunks of row a (lanes differing in bits 4,5) — DS
        m |= (uint32_t)__shfl_xor((int)m, 16);
        m |= (uint32_t)__shfl_xor((int)m, 32);
        int cm = row16_sumi(__popc(m));        // sum rowcounts over the 16 a's

        // z reduction over a within each 16-lane row — DPP
        float s0 = row16_sum(v0.x);
        float s1 = row16_sum(v0.y);
        float s2 = row16_sum(v0.z);
        float s3 = row16_sum(v0.w);

        if (writer) {
            int j = lane & 3;
            float dsel = (j == 0) ? s0 : (j == 1) ? s1 : (j == 2) ? s2 : s3;
            out[n0 * NTPL + tl] = 0.0625f * dsel + A + (float)cm * (1.f / 256.f) * Bc;
        }

        n0 = n1; nbr0 = nbr1; v0 = v1; cv0 = cv1;
        n1 = n2; nbr1 = nbr2;
    }
}

// ---------------- fallback path (proven R2 kernels, ws too small) ------------
__global__ void ltfwg_prep(const float* __restrict__ tmpl,
                           const float* __restrict__ tfeat,
                           float* __restrict__ ws) {
    const int t   = blockIdx.x;
    const int tid = threadIdx.x;
    float s = 0.f, ssq = 0.f;
    #pragma unroll
    for (int m = 0; m < MTPL; ++m) {
        float v = tfeat[t * (MTPL * NFEAT) + m * NFEAT + tid];
        s += v;
        ssq += v * v;
    }
    ws[TMEAN_OFF + t * NFEAT + tid] = s * 0.125f;
    __shared__ float red[128];
    red[tid] = ssq;
    __syncthreads();
    for (int o = 64; o > 0; o >>= 1) {
        if (tid < o) red[tid] += red[tid + o];
        __syncthreads();
    }
    if (tid == 0) ws[TSQ_OFF + t] = red[0] * 0.125f;
    if (tid < 64) {
        float v = tmpl[t * 64 + tid];
        float sv = v, sv2 = v * v;
        #pragma unroll
        for (int off = 32; off >= 1; off >>= 1) {
            sv  += __shfl_xor(sv, off);
            sv2 += __shfl_xor(sv2, off);
        }
        if (tid == 0) {
            ws[MCT_OFF + t]  = sv  * (1.f / 64.f);
            ws[MCT2_OFF + t] = sv2 * (1.f / 64.f);
        }
    }
}

__global__ __launch_bounds__(256, 4)
void ltfwg_fallback(const float* __restrict__ x, const int* __restrict__ dst,
                    const float* __restrict__ ws, float* __restrict__ out) {
    const int lane   = threadIdx.x & 63;
    const int wave   = (blockIdx.x * blockDim.x + threadIdx.x) >> 6;
    const int nwaves = (gridDim.x * blockDim.x) >> 6;
    float tm0[NTPL], tm1[NTPL];
    #pragma unroll
    for (int t = 0; t < NTPL; ++t) {
        float2 tv = ((const float2*)(ws + TMEAN_OFF + t * NFEAT))[lane];
        tm0[t] = tv.x;
        tm1[t] = tv.y;
    }
    const int tl = lane & 15;
    const float A  = 0.5f * (ws[TSQ_OFF + tl] + ws[MCT2_OFF + tl]);
    const float Bc = 0.5f - ws[MCT_OFF + tl];
    for (int n = wave; n < N_NODES; n += nwaves) {
        const int nbr = dst[n * KDEG + (lane & 15)];
        float fs0 = 0.f, fs1 = 0.f, sqa = 0.f;
        #pragma unroll
        for (int aa = 0; aa < KDEG; ++aa) {
            int nid = __shfl(nbr, aa);
            float2 fv = ((const float2*)x)[nid * (NFEAT / 2) + lane];
            fs0 += fv.x; fs1 += fv.y;
            sqa += fv.x * fv.x + fv.y * fv.y;
        }
        float dotp[NTPL];
        #pragma unroll
        for (int t = 0; t < NTPL; ++t) dotp[t] = fs0 * tm0[t] + fs1 * tm1[t];
        int nida = __shfl(nbr, lane >> 2);
        int4 cv = ((const int4*)(dst + nida * KDEG))[lane & 3];
        uint32_t m = 0;
        #pragma unroll
        for (int b = 0; b < KDEG; ++b) {
            int vb = __shfl(nbr, b);
            uint32_t hit = (uint32_t)((cv.x == vb) | (cv.y == vb) |
                                      (cv.z == vb) | (cv.w == vb));
            m |= hit << b;
        }
        m |= (uint32_t)__shfl_xor((int)m, 1);
        m |= (uint32_t)__shfl_xor((int)m, 2);
        float cnt = (float)__popc(m);
        #pragma unroll
        for (int off = 32; off >= 1; off >>= 1) {
            sqa += __shfl_xor(sqa, off);
            cnt += __shfl_xor(cnt, off);
            #pragma unroll
            for (int t = 0; t < NTPL; ++t) dotp[t] += __shfl_xor(dotp[t], off);
        }
        float dsel = dotp[0];
        #pragma unroll
        for (int t = 1; t < NTPL; ++t) dsel = (lane == t) ? dotp[t] : dsel;
        if (lane < NTPL) {
            float mC = cnt * (1.0f / 1024.0f);
            out[n * NTPL + lane] = 0.03125f * sqa - 0.0625f * dsel + A + mC * Bc;
        }
    }
}

extern "C" void kernel_launch(void* const* d_in, const int* in_sizes, int n_in,
                              void* d_out, int out_size, void* d_ws, size_t ws_size,
                              hipStream_t stream) {
    const float* x     = (const float*)d_in[0];
    const int*   edge  = (const int*)d_in[1];
    const float* tmpl  = (const float*)d_in[2];
    const float* tfeat = (const float*)d_in[3];
    float* ws  = (float*)d_ws;
    float* out = (float*)d_out;
    const int* dst = edge + (N_NODES * KDEG);

    if (ws_size >= WS_BYTES) {
        ltfwg_zbuild<<<NTILES, 256, 0, stream>>>(x, dst, tmpl, tfeat, ws);
        ltfwg_gather<<<2048, 256, 0, stream>>>(dst, ws, out);
    } else {
        ltfwg_prep<<<NTPL, 128, 0, stream>>>(tmpl, tfeat, ws);
        ltfwg_fallback<<<1024, 256, 0, stream>>>(x, dst, ws, out);
    }
}